// Round 7
// baseline (275.290 us; speedup 1.0000x reference)
//
#include <hip/hip_runtime.h>

#define LAMBDA_COORD 5.0f
#define LAMBDA_NOOBJ 0.5f
#define DD 30
#define BLOCK 256
#define TCELLS 32                  // cells per tile
#define F4T (TCELLS * DD / 4)      // 240 float4 per input per tile
#define GRID 2048                  // 8 blocks/CU * 256 CU: all resident
#define NTILES (802816 / TCELLS)   // 25088 = 12*2048 + 512
#define NITER 13                   // 12 full sweeps + partial tail

__device__ __forceinline__ float iou_t(float tx, float ty, float tw, float th,
                                       float px, float py, float pw, float ph) {
    float xl = fmaxf(tx - tw * 0.5f, px - pw * 0.5f);
    float yt = fmaxf(ty - th * 0.5f, py - ph * 0.5f);
    float xr = fminf(tx + tw * 0.5f, px + pw * 0.5f);
    float yb = fminf(ty + th * 0.5f, py + ph * 0.5f);
    bool valid = (xr >= xl) && (yb >= yt);
    float inter = (xr - xl) * (yb - yt);
    float uni = tw * th + pw * ph - inter;
    float safe = (uni == 0.0f) ? 1.0f : uni;
    return valid ? (inter / safe) : 0.0f;
}

__global__ __launch_bounds__(BLOCK, 8) void yolo_loss_kernel(
    const float* __restrict__ pred, const float* __restrict__ targ,
    float* __restrict__ out) {
    // double-buffered: 2 * (3840 + 3840) = 15360 B -> 8 blocks/CU, 100% occupancy
    __shared__ __align__(16) float sp[2][TCELLS * DD];
    __shared__ __align__(16) float st[2][TCELLS * DD];
    __shared__ float wpart[BLOCK / 64];

    const int tid = threadIdx.x;
    const int bid = blockIdx.x;
    const int li = (tid < F4T) ? tid : (F4T - 1);   // clamp: regs always defined

    // compute-lane mapping: lanes 0..7 of each wave own one cell
    const int wv = tid >> 6, lane = tid & 63;
    const bool is_comp = lane < (TCELLS / 4);       // 8 lanes * 4 waves = 32 cells
    const int mycell = lane * 4 + wv;

    const float4* p4 = (const float4*)pred;
    const float4* t4p = (const float4*)targ;

    // ---- prologue: load tile for iter 0 (tile = bid, always < NTILES) ----
    float4 RP = p4[(size_t)bid * F4T + li];
    float4 RT = t4p[(size_t)bid * F4T + li];

    float acc = 0.0f;

    for (int it = 0; it < NITER; ++it) {
        const int tile = it * GRID + bid;          // sliding-window assignment
        const bool active = tile < NTILES;          // block-uniform
        const int cur = it & 1;

        // phase 1: staged regs -> LDS (vmcnt wait for this tile's loads lands
        // here, one full compute phase after issue in steady state)
        if (active) {
            ((float4*)sp[cur])[li] = RP;
            ((float4*)st[cur])[li] = RT;
        }
        __syncthreads();   // block-uniform; vmcnt already drained -> lgkm-only

        // phase 2: issue next tile's loads AFTER the barrier (never drained by it)
        const int ntile = (it + 1) * GRID + bid;
        if (it + 1 < NITER && ntile < NTILES) {
            RP = p4[(size_t)ntile * F4T + li];
            RT = t4p[(size_t)ntile * F4T + li];
        }

        // phase 3: compute this tile from LDS (32 threads; VALU is ~free)
        if (active && is_comp) {
            const float* p = &sp[cur][mycell * DD];
            const float* t = &st[cur][mycell * DD];

            float tv4 = t[4];
            float obj = (tv4 > 0.0f) ? 1.0f : 0.0f;
            float noobj = (tv4 == 0.0f) ? 1.0f : 0.0f;

            float cls = 0.0f;
#pragma unroll
            for (int k = 10; k < 30; ++k) {
                float d = t[k] - p[k];
                cls += d * d;
            }
            cls *= obj;

            float d4 = tv4 - p[4];
            float conf_noobj = noobj * d4 * d4;

            float tx = t[0], ty = t[1], tw = t[2], th = t[3];
            float iou1 = iou_t(tx, ty, tw, th, p[0], p[1], p[2], p[3]);
            float iou2 = iou_t(tx, ty, tw, th, p[5], p[6], p[7], p[8]);
            float resp1 = (iou1 > iou2) ? 1.0f : 0.0f;
            float m1 = obj * resp1;
            float m2 = obj * (1.0f - resp1);

            float e1 = iou1 - p[4];
            float e2 = iou2 - p[9];
            float conf_obj = m1 * e1 * e1 + m2 * e2 * e2;

            float dx1 = tx - p[0], dy1 = ty - p[1];
            float dx2 = tx - p[5], dy2 = ty - p[6];
            float xy = m1 * (dx1 * dx1 + dy1 * dy1) + m2 * (dx2 * dx2 + dy2 * dy2);

            float dw1 = tw - p[2], dh1 = th - p[3];
            float dw2 = tw - p[7], dh2 = th - p[8];
            float wh = m1 * (dw1 * dw1 + dh1 * dh1) + m2 * (dw2 * dw2 + dh2 * dh2);

            acc += LAMBDA_COORD * (xy + wh) + conf_obj + LAMBDA_NOOBJ * conf_noobj + cls;
        }
    }

    // ---- block reduction: wave shuffles -> LDS partials -> one atomic ----
#pragma unroll
    for (int off = 32; off > 0; off >>= 1) acc += __shfl_down(acc, off);
    if (lane == 0) wpart[wv] = acc;
    __syncthreads();
    if (tid == 0) {
        float s = wpart[0] + wpart[1] + wpart[2] + wpart[3];
        atomicAdd(out, s * (1.0f / 16384.0f));
    }
}

extern "C" void kernel_launch(void* const* d_in, const int* in_sizes, int n_in,
                              void* d_out, int out_size, void* d_ws, size_t ws_size,
                              hipStream_t stream) {
    const float* pred = (const float*)d_in[0];  // y
    const float* targ = (const float*)d_in[1];  // gt
    float* out = (float*)d_out;

    hipMemsetAsync(out, 0, sizeof(float), stream);

    yolo_loss_kernel<<<GRID, BLOCK, 0, stream>>>(pred, targ, out);
}

// Round 8
// 263.292 us; speedup vs baseline: 1.0456x; 1.0456x over previous
//
#include <hip/hip_runtime.h>

#define LAMBDA_COORD 5.0f
#define LAMBDA_NOOBJ 0.5f
#define DD 30
#define BLOCK 256

typedef float __attribute__((ext_vector_type(4))) f4v;

// compile-time element extraction from an f4v[15] register array
#define EL(A, k) (A[(k) >> 2][(k) & 3])

__device__ __forceinline__ float iou_t(float tx, float ty, float tw, float th,
                                       float px, float py, float pw, float ph) {
    float xl = fmaxf(tx - tw * 0.5f, px - pw * 0.5f);
    float yt = fmaxf(ty - th * 0.5f, py - ph * 0.5f);
    float xr = fminf(tx + tw * 0.5f, px + pw * 0.5f);
    float yb = fminf(ty + th * 0.5f, py + ph * 0.5f);
    bool valid = (xr >= xl) && (yb >= yt);
    float inter = (xr - xl) * (yb - yt);
    float uni = tw * th + pw * ph - inter;
    float safe = (uni == 0.0f) ? 1.0f : uni;
    return valid ? (inter / safe) : 0.0f;
}

// loss of one cell whose 30 channels start at flat index B (B = 0 or 30)
template <int B>
__device__ __forceinline__ float cell_loss(const f4v (&P)[15], const f4v (&T)[15]) {
    float t4 = EL(T, B + 4);
    float obj = (t4 > 0.0f) ? 1.0f : 0.0f;
    float noobj = (t4 == 0.0f) ? 1.0f : 0.0f;

    float cls = 0.0f;
#pragma unroll
    for (int k = 10; k < 30; ++k) {
        float d = EL(T, B + k) - EL(P, B + k);
        cls += d * d;
    }
    cls *= obj;

    float d4 = t4 - EL(P, B + 4);
    float conf_noobj = noobj * d4 * d4;

    float tx = EL(T, B + 0), ty = EL(T, B + 1), tw = EL(T, B + 2), th = EL(T, B + 3);
    float p0 = EL(P, B + 0), p1 = EL(P, B + 1), p2 = EL(P, B + 2), p3 = EL(P, B + 3);
    float p4 = EL(P, B + 4), p5 = EL(P, B + 5), p6 = EL(P, B + 6), p7 = EL(P, B + 7);
    float p8 = EL(P, B + 8), p9 = EL(P, B + 9);

    float iou1 = iou_t(tx, ty, tw, th, p0, p1, p2, p3);
    float iou2 = iou_t(tx, ty, tw, th, p5, p6, p7, p8);
    float resp1 = (iou1 > iou2) ? 1.0f : 0.0f;
    float m1 = obj * resp1;
    float m2 = obj * (1.0f - resp1);

    float e1 = iou1 - p4;
    float e2 = iou2 - p9;
    float conf_obj = m1 * e1 * e1 + m2 * e2 * e2;

    float dx1 = tx - p0, dy1 = ty - p1;
    float dx2 = tx - p5, dy2 = ty - p6;
    float xy = m1 * (dx1 * dx1 + dy1 * dy1) + m2 * (dx2 * dx2 + dy2 * dy2);

    float dw1 = tw - p2, dh1 = th - p3;
    float dw2 = tw - p7, dh2 = th - p8;
    float wh = m1 * (dw1 * dw1 + dh1 * dh1) + m2 * (dw2 * dw2 + dh2 * dh2);

    return LAMBDA_COORD * (xy + wh) + conf_obj + LAMBDA_NOOBJ * conf_noobj + cls;
}

__global__ __launch_bounds__(BLOCK, 2) void yolo_loss_kernel(
    const float* __restrict__ pred, const float* __restrict__ targ,
    float* __restrict__ out) {
    __shared__ float wpart[BLOCK / 64];

    const int tid = threadIdx.x;
    const size_t pair = (size_t)blockIdx.x * BLOCK + tid;  // cell-pair index

    // cell-pair = 2 cells = 60 floats = 240 B = 15 aligned float4
    const f4v* gp = (const f4v*)pred + pair * 15;
    const f4v* gt = (const f4v*)targ + pair * 15;

    f4v P[15], T[15];
#pragma unroll
    for (int j = 0; j < 15; ++j) P[j] = __builtin_nontemporal_load(gp + j);
#pragma unroll
    for (int j = 0; j < 15; ++j) T[j] = __builtin_nontemporal_load(gt + j);

    float loss = cell_loss<0>(P, T) + cell_loss<30>(P, T);

    // ---- 64-lane wave reduction, then block reduction, one atomic/block ----
#pragma unroll
    for (int off = 32; off > 0; off >>= 1) loss += __shfl_down(loss, off);
    if ((tid & 63) == 0) wpart[tid >> 6] = loss;
    __syncthreads();
    if (tid == 0) {
        float s = wpart[0] + wpart[1] + wpart[2] + wpart[3];
        atomicAdd(out, s * (1.0f / 16384.0f));
    }
}

extern "C" void kernel_launch(void* const* d_in, const int* in_sizes, int n_in,
                              void* d_out, int out_size, void* d_ws, size_t ws_size,
                              hipStream_t stream) {
    const float* pred = (const float*)d_in[0];  // y
    const float* targ = (const float*)d_in[1];  // gt
    float* out = (float*)d_out;

    hipMemsetAsync(out, 0, sizeof(float), stream);

    const int cells = in_sizes[0] / DD;     // 802816
    const int pairs = cells / 2;            // 401408
    const int grid = pairs / BLOCK;         // 1568 (exact)
    yolo_loss_kernel<<<grid, BLOCK, 0, stream>>>(pred, targ, out);
}

// Round 9
// 205.490 us; speedup vs baseline: 1.3397x; 1.2813x over previous
//
#include <hip/hip_runtime.h>

#define LAMBDA_COORD 5.0f
#define LAMBDA_NOOBJ 0.5f
#define DD 30
#define BLOCK 256

__device__ __forceinline__ float iou_t(float tx, float ty, float tw, float th,
                                       float px, float py, float pw, float ph) {
    float xl = fmaxf(tx - tw * 0.5f, px - pw * 0.5f);
    float yt = fmaxf(ty - th * 0.5f, py - ph * 0.5f);
    float xr = fminf(tx + tw * 0.5f, px + pw * 0.5f);
    float yb = fminf(ty + th * 0.5f, py + ph * 0.5f);
    bool valid = (xr >= xl) && (yb >= yt);
    float inter = (xr - xl) * (yb - yt);
    float uni = tw * th + pw * ph - inter;
    float safe = (uni == 0.0f) ? 1.0f : uni;
    return valid ? (inter / safe) : 0.0f;
}

// element k of a float2[15] register array (k is a compile-time constant after unroll)
#define EL(A, k) (((k) & 1) ? A[(k) >> 1].y : A[(k) >> 1].x)

__global__ __launch_bounds__(BLOCK, 4) void yolo_loss_kernel(
    const float* __restrict__ pred, const float* __restrict__ targ,
    float* __restrict__ out) {
    __shared__ float wpart[BLOCK / 64];

    const int tid = threadIdx.x;
    const size_t cell = (size_t)blockIdx.x * BLOCK + tid;

    // ---- direct global -> register load: 15 x float2 per input, no LDS ----
    const float2* gp = (const float2*)(pred + cell * DD);
    const float2* gt = (const float2*)(targ + cell * DD);
    float2 P[15], T[15];
#pragma unroll
    for (int j = 0; j < 15; ++j) P[j] = gp[j];
#pragma unroll
    for (int j = 0; j < 15; ++j) T[j] = gt[j];

    // ---- per-cell loss, all from registers ----
    float t4 = EL(T, 4);
    float obj = (t4 > 0.0f) ? 1.0f : 0.0f;
    float noobj = (t4 == 0.0f) ? 1.0f : 0.0f;

    float cls = 0.0f;
#pragma unroll
    for (int j = 5; j < 15; ++j) {   // channels 10..29
        float dx = T[j].x - P[j].x;
        float dy = T[j].y - P[j].y;
        cls += dx * dx + dy * dy;
    }
    cls *= obj;

    float d4 = t4 - EL(P, 4);
    float conf_noobj = noobj * d4 * d4;

    float tx = EL(T, 0), ty = EL(T, 1), tw = EL(T, 2), th = EL(T, 3);
    float p0 = EL(P, 0), p1 = EL(P, 1), p2 = EL(P, 2), p3 = EL(P, 3);
    float p4 = EL(P, 4), p5 = EL(P, 5), p6 = EL(P, 6), p7 = EL(P, 7);
    float p8 = EL(P, 8), p9 = EL(P, 9);

    float iou1 = iou_t(tx, ty, tw, th, p0, p1, p2, p3);
    float iou2 = iou_t(tx, ty, tw, th, p5, p6, p7, p8);
    float resp1 = (iou1 > iou2) ? 1.0f : 0.0f;
    float m1 = obj * resp1;
    float m2 = obj * (1.0f - resp1);

    float e1 = iou1 - p4;
    float e2 = iou2 - p9;
    float conf_obj = m1 * e1 * e1 + m2 * e2 * e2;

    float dx1 = tx - p0, dy1 = ty - p1;
    float dx2 = tx - p5, dy2 = ty - p6;
    float xy = m1 * (dx1 * dx1 + dy1 * dy1) + m2 * (dx2 * dx2 + dy2 * dy2);

    float dw1 = tw - p2, dh1 = th - p3;
    float dw2 = tw - p7, dh2 = th - p8;
    float wh = m1 * (dw1 * dw1 + dh1 * dh1) + m2 * (dw2 * dw2 + dh2 * dh2);

    float loss = LAMBDA_COORD * (xy + wh) + conf_obj + LAMBDA_NOOBJ * conf_noobj + cls;

    // ---- 64-lane wave reduction, then block reduction, one atomic/block ----
#pragma unroll
    for (int off = 32; off > 0; off >>= 1) loss += __shfl_down(loss, off);
    if ((tid & 63) == 0) wpart[tid >> 6] = loss;
    __syncthreads();
    if (tid == 0) {
        float s = wpart[0] + wpart[1] + wpart[2] + wpart[3];
        atomicAdd(out, s * (1.0f / 16384.0f));
    }
}

extern "C" void kernel_launch(void* const* d_in, const int* in_sizes, int n_in,
                              void* d_out, int out_size, void* d_ws, size_t ws_size,
                              hipStream_t stream) {
    const float* pred = (const float*)d_in[0];  // y
    const float* targ = (const float*)d_in[1];  // gt
    float* out = (float*)d_out;

    hipMemsetAsync(out, 0, sizeof(float), stream);

    const int cells = in_sizes[0] / DD;   // 802816
    const int grid = cells / BLOCK;       // 3136 (exact)
    yolo_loss_kernel<<<grid, BLOCK, 0, stream>>>(pred, targ, out);
}